// Round 16
// baseline (4224.204 us; speedup 1.0000x reference)
//
#include <hip/hip_runtime.h>
#include <hip/hip_bf16.h>
#include <stdint.h>
#include <math.h>

typedef __attribute__((ext_vector_type(4))) float f32x4;

#define NB 64      // batch
#define NT 63      // time steps (captions[:, :-1])
#define NE 512     // embed dim
#define NH 512     // hidden dim
#define NV 32000   // vocab
#define NG 2048    // 4*H gates

__device__ __forceinline__ float sigm(float x) { return 1.f / (1.f + expf(-x)); }

// ---- kernel 1: SHOWN init: h0 = tanh(enc@Wh^T+bh), c0 = tanh(enc@Wc^T+bc) ---
__global__ __launch_bounds__(256) void k_init(
    const float* __restrict__ enc, const float* __restrict__ Wh, const float* __restrict__ bh,
    const float* __restrict__ Wc, const float* __restrict__ bc,
    float* __restrict__ c0, float* __restrict__ h0) {
  int b = blockIdx.x;
  __shared__ float se[NE];
  for (int e = threadIdx.x; e < NE; e += 256) se[e] = enc[b * NE + e];
  __syncthreads();
  for (int j = threadIdx.x; j < NH; j += 256) {
    float dh = 0.f, dc = 0.f;
    const float* wh = Wh + (size_t)j * NE;
    const float* wc = Wc + (size_t)j * NE;
    for (int e = 0; e < NE; e += 4) {
      f32x4 vh = *(const f32x4*)(wh + e);
      f32x4 vc = *(const f32x4*)(wc + e);
#pragma unroll
      for (int u = 0; u < 4; ++u) {
        float x = se[e + u];
        dh += x * vh[u];
        dc += x * vc[u];
      }
    }
    h0[b * NH + j] = tanhf(dh + bh[j]);
    c0[b * NH + j] = tanhf(dc + bc[j]);
  }
}

// ---- kernel 2 (f32): xp[t][b][g] = emb(cap[b][t]) @ W_ih^T + b_ih + b_hh ----
__global__ __launch_bounds__(256) void k_xp(
    const int* __restrict__ cap, const float* __restrict__ emb,
    const float* __restrict__ Wih, const float* __restrict__ bih, const float* __restrict__ bhh,
    float* __restrict__ xp) {
  int t = blockIdx.x;
  int g0 = blockIdx.y * 64;
  int b = threadIdx.x & 63;
  int gg = threadIdx.x >> 6;
  __shared__ float wl[64 * 32];

  int tok = cap[b * 64 + t];          // captions (64,64) row-major
  const float* er = emb + (size_t)tok * NE;

  float acc[16];
#pragma unroll
  for (int i = 0; i < 16; ++i) acc[i] = 0.f;

  for (int k0 = 0; k0 < NE; k0 += 32) {
    __syncthreads();
#pragma unroll
    for (int i = 0; i < 2; ++i) {
      int s = threadIdx.x + 256 * i;
      int gr = s >> 3, c4 = s & 7;
      *(f32x4*)(wl + gr * 32 + c4 * 4) =
          *(const f32x4*)(Wih + (size_t)(g0 + gr) * NE + k0 + c4 * 4);
    }
    __syncthreads();
    f32x4 e4[8];
#pragma unroll
    for (int u = 0; u < 8; ++u) e4[u] = *(const f32x4*)(er + k0 + u * 4);
#pragma unroll
    for (int k4 = 0; k4 < 8; ++k4) {
#pragma unroll
      for (int i = 0; i < 16; ++i) {
        f32x4 w = *(const f32x4*)(wl + (gg * 16 + i) * 32 + k4 * 4);
#pragma unroll
        for (int u = 0; u < 4; ++u) acc[i] += e4[k4][u] * w[u];
      }
    }
  }
  size_t rb = ((size_t)(t * NB) + b) * NG + g0 + gg * 16;
#pragma unroll
  for (int i = 0; i < 16; ++i) {
    int g = g0 + gg * 16 + i;
    xp[rb + i] = acc[i] + bih[g] + bhh[g];
  }
}

// ---- kernel 3a (f32): one LSTM step, xp precomputed -------------------------
__global__ __launch_bounds__(256) void k_step(
    const float* __restrict__ xp_t, const float* __restrict__ Whh,
    const float* __restrict__ h_in, float* __restrict__ c,
    float* __restrict__ h_out, float* __restrict__ hs_t) {
  int j0 = blockIdx.x * 2;
  int tid = threadIdx.x;
  int b = tid & 63;
  int jl = (tid >> 6) & 1;
  int gh = tid >> 7;
  __shared__ float w8[8 * 512];
  __shared__ float hl[64 * 128];
  __shared__ float gbuf[64 * 2 * 4];

#pragma unroll
  for (int i = 0; i < 4; ++i) {
    int s = tid + 256 * i;
    int r = s >> 7, c4 = s & 127;
    int g = r >> 1, jj = r & 1;
    *(f32x4*)(w8 + r * 512 + c4 * 4) =
        *(const f32x4*)(Whh + (size_t)(g * NH + j0 + jj) * NH + c4 * 4);
  }

  float accA = 0.f, accB = 0.f;
  int rA = 4 * gh + jl;
  int rB = rA + 2;
  int Cb = b & 31;

  for (int k0 = 0; k0 < NH; k0 += 128) {
    __syncthreads();
#pragma unroll
    for (int i = 0; i < 8; ++i) {
      int s = tid + 256 * i;
      int row = s >> 5, c4 = s & 31;
      f32x4 v = *(const f32x4*)(h_in + (size_t)row * NH + k0 + c4 * 4);
      *(f32x4*)(hl + row * 128 + ((c4 ^ (row & 31)) * 4)) = v;
    }
    __syncthreads();
#pragma unroll 8
    for (int k4 = 0; k4 < 32; ++k4) {
      f32x4 hv = *(const f32x4*)(hl + b * 128 + ((k4 ^ Cb) * 4));
      f32x4 wa = *(const f32x4*)(w8 + rA * 512 + k0 + k4 * 4);
      f32x4 wb = *(const f32x4*)(w8 + rB * 512 + k0 + k4 * 4);
#pragma unroll
      for (int u = 0; u < 4; ++u) {
        accA += hv[u] * wa[u];
        accB += hv[u] * wb[u];
      }
    }
  }

  int j = j0 + jl;
  accA += xp_t[(size_t)b * NG + (2 * gh) * NH + j];
  accB += xp_t[(size_t)b * NG + (2 * gh + 1) * NH + j];
  gbuf[(b * 2 + jl) * 4 + 2 * gh] = accA;
  gbuf[(b * 2 + jl) * 4 + 2 * gh + 1] = accB;
  __syncthreads();

  if (tid < 128) {
    int bb = tid & 63, jj = tid >> 6;
    int jx = j0 + jj;
    float gi = gbuf[(bb * 2 + jj) * 4 + 0];
    float gf = gbuf[(bb * 2 + jj) * 4 + 1];
    float gG = gbuf[(bb * 2 + jj) * 4 + 2];
    float go = gbuf[(bb * 2 + jj) * 4 + 3];
    float cn = sigm(gf) * c[bb * NH + jx] + sigm(gi) * tanhf(gG);
    c[bb * NH + jx] = cn;
    float h = sigm(go) * tanhf(cn);
    h_out[bb * NH + jx] = h;
    hs_t[bb * NH + jx] = h;
  }
}

// ---- kernel 3b (f32): fused LSTM step, NO xp buffer needed ------------------
__global__ __launch_bounds__(256) void k_step_f(
    const int* __restrict__ cap, int t, const float* __restrict__ emb,
    const float* __restrict__ Wih, const float* __restrict__ Whh,
    const float* __restrict__ bih, const float* __restrict__ bhh,
    const float* __restrict__ h_in, float* __restrict__ c,
    float* __restrict__ h_out, float* __restrict__ hs_t) {
  int j0 = blockIdx.x * 2;
  int tid = threadIdx.x;
  int b = tid & 63;
  int jl = (tid >> 6) & 1;
  int gh = tid >> 7;
  __shared__ float w16[8 * 1024];
  __shared__ float xl[64 * 64];
  __shared__ float gbuf[512];
  __shared__ int   tokL[64];

  if (tid < 64) tokL[tid] = cap[tid * 64 + t];

#pragma unroll
  for (int i = 0; i < 8; ++i) {
    int s = tid + 256 * i;
    int r = s >> 8, c4 = s & 255;
    int g = r >> 1, jj = r & 1;
    int col = c4 * 4;
    const float* src = (col < 512)
        ? (Wih + (size_t)(g * NH + j0 + jj) * NE + col)
        : (Whh + (size_t)(g * NH + j0 + jj) * NH + (col - 512));
    *(f32x4*)(w16 + r * 1024 + col) = *(const f32x4*)src;
  }

  float accA = 0.f, accB = 0.f;
  int rA = 4 * gh + jl;
  int rB = rA + 2;
  int Cb = b & 15;

  for (int kc = 0; kc < 16; ++kc) {
    __syncthreads();
#pragma unroll
    for (int i = 0; i < 4; ++i) {
      int s = tid + 256 * i;
      int row = s >> 4, c4 = s & 15;
      const float* src = (kc < 8)
          ? (emb + (size_t)tokL[row] * NE + kc * 64 + c4 * 4)
          : (h_in + (size_t)row * NH + (kc - 8) * 64 + c4 * 4);
      *(f32x4*)(xl + row * 64 + ((c4 ^ (row & 15)) * 4)) = *(const f32x4*)src;
    }
    __syncthreads();
#pragma unroll
    for (int k4 = 0; k4 < 16; ++k4) {
      f32x4 hv = *(const f32x4*)(xl + b * 64 + ((k4 ^ Cb) * 4));
      f32x4 wa = *(const f32x4*)(w16 + rA * 1024 + kc * 64 + k4 * 4);
      f32x4 wb = *(const f32x4*)(w16 + rB * 1024 + kc * 64 + k4 * 4);
#pragma unroll
      for (int u = 0; u < 4; ++u) {
        accA += hv[u] * wa[u];
        accB += hv[u] * wb[u];
      }
    }
  }

  int j = j0 + jl;
  accA += bih[(2 * gh) * NH + j] + bhh[(2 * gh) * NH + j];
  accB += bih[(2 * gh + 1) * NH + j] + bhh[(2 * gh + 1) * NH + j];
  gbuf[(b * 2 + jl) * 4 + 2 * gh] = accA;
  gbuf[(b * 2 + jl) * 4 + 2 * gh + 1] = accB;
  __syncthreads();

  if (tid < 128) {
    int bb = tid & 63, jj = tid >> 6;
    int jx = j0 + jj;
    float gi = gbuf[(bb * 2 + jj) * 4 + 0];
    float gf = gbuf[(bb * 2 + jj) * 4 + 1];
    float gG = gbuf[(bb * 2 + jj) * 4 + 2];
    float go = gbuf[(bb * 2 + jj) * 4 + 3];
    float cn = sigm(gf) * c[bb * NH + jx] + sigm(gi) * tanhf(gG);
    c[bb * NH + jx] = cn;
    float h = sigm(go) * tanhf(cn);
    h_out[bb * NH + jx] = h;
    hs_t[bb * NH + jx] = h;
  }
}

// ---- kernel 4 (pure f32 VALU), FLOAT32 output, (b,t,v) layout ---------------
__global__ __launch_bounds__(256) void k_logits_v(
    const float* __restrict__ hs, const float* __restrict__ Wout,
    const float* __restrict__ bout, float* __restrict__ out) {
  int m0 = blockIdx.x * 32;
  int v = blockIdx.y * 256 + threadIdx.x;
  __shared__ float hl[32][NH];
  for (int i = threadIdx.x; i < 32 * NH; i += 256) {
    int mm = i >> 9, k = i & 511;
    hl[mm][k] = hs[(size_t)(m0 + mm) * NH + k];
  }
  __syncthreads();

  float acc[32];
#pragma unroll
  for (int mm = 0; mm < 32; ++mm) acc[mm] = 0.f;

  const float* wr = Wout + (size_t)v * NH;
  for (int k = 0; k < NH; k += 4) {
    f32x4 w = *(const f32x4*)(wr + k);
#pragma unroll
    for (int mm = 0; mm < 32; ++mm)
      acc[mm] += w[0] * hl[mm][k] + w[1] * hl[mm][k + 1] +
                 w[2] * hl[mm][k + 2] + w[3] * hl[mm][k + 3];
  }
  float bo = bout[v];
#pragma unroll
  for (int mm = 0; mm < 32; ++mm) {
    int m = m0 + mm;
    int t = m >> 6, b = m & 63;
    out[(size_t)b * (NT * NV) + (size_t)t * NV + v] = acc[mm] + bo;   // f32!
  }
}

extern "C" void kernel_launch(void* const* d_in, const int* in_sizes, int n_in,
                              void* d_out, int out_size, void* d_ws, size_t ws_size,
                              hipStream_t stream) {
  const float* enc  = (const float*)d_in[0];
  const int*   cap  = (const int*)d_in[1];
  const float* emb  = (const float*)d_in[2];
  const float* Wih  = (const float*)d_in[3];
  const float* Whh  = (const float*)d_in[4];
  const float* bih  = (const float*)d_in[5];
  const float* bhh  = (const float*)d_in[6];
  const float* Wh   = (const float*)d_in[7];
  const float* bh   = (const float*)d_in[8];
  const float* Wc   = (const float*)d_in[9];
  const float* bc   = (const float*)d_in[10];
  const float* Wout = (const float*)d_in[11];
  const float* bout = (const float*)d_in[12];
  float* out = (float*)d_out;   // FLOAT32 output (round-15 probe finding)

  char* ws = (char*)d_ws;
  constexpr size_t C_OFF  = 0;
  constexpr size_t HA_OFF = C_OFF + (size_t)NB * NH * 4;          // 131072
  constexpr size_t HB_OFF = HA_OFF + (size_t)NB * NH * 4;         // 262144
  constexpr size_t HS_OFF = HB_OFF + (size_t)NB * NH * 4;         // 393216
  constexpr size_t XP_OFF = HS_OFF + (size_t)(NT * NB) * NH * 4;  // 8,650,752
  constexpr size_t NEED_XP = XP_OFF + (size_t)NT * NB * NG * 4;   // 41,680,896
  float* c  = (float*)(ws + C_OFF);
  float* hA = (float*)(ws + HA_OFF);
  float* hB = (float*)(ws + HB_OFF);
  float* hs = (float*)(ws + HS_OFF);
  float* xp = (float*)(ws + XP_OFF);

  k_init<<<NB, 256, 0, stream>>>(enc, Wh, bh, Wc, bc, c, hA);

  if (ws_size >= NEED_XP) {
    dim3 g2(NT, NG / 64);
    k_xp<<<g2, 256, 0, stream>>>(cap, emb, Wih, bih, bhh, xp);
    for (int t = 0; t < NT; ++t) {
      const float* h_in = (t & 1) ? hB : hA;
      float* h_out      = (t & 1) ? hA : hB;
      k_step<<<256, 256, 0, stream>>>(xp + (size_t)t * NB * NG, Whh, h_in, c,
                                      h_out, hs + (size_t)t * NB * NH);
    }
  } else {
    for (int t = 0; t < NT; ++t) {
      const float* h_in = (t & 1) ? hB : hA;
      float* h_out      = (t & 1) ? hA : hB;
      k_step_f<<<256, 256, 0, stream>>>(cap, t, emb, Wih, Whh, bih, bhh, h_in, c,
                                        h_out, hs + (size_t)t * NB * NH);
    }
  }

  dim3 g4(126, 125);
  k_logits_v<<<g4, 256, 0, stream>>>(hs, Wout, bout, out);
}

// Round 17
// 1394.352 us; speedup vs baseline: 3.0295x; 3.0295x over previous
//
#include <hip/hip_runtime.h>
#include <hip/hip_bf16.h>
#include <stdint.h>
#include <math.h>

typedef __attribute__((ext_vector_type(4))) float f32x4;
typedef __attribute__((ext_vector_type(8))) short short8;   // 8 bf16

#define NB 64      // batch
#define NT 63      // time steps (captions[:, :-1])
#define NE 512     // embed dim
#define NH 512     // hidden dim
#define NV 32000   // vocab
#define NG 2048    // 4*H gates

__device__ __forceinline__ float sigm(float x) { return 1.f / (1.f + expf(-x)); }
__device__ __forceinline__ unsigned short f2b(float f) {   // f32 -> bf16 RNE
  union { float f; uint32_t u; } x; x.f = f;
  uint32_t r = x.u + 0x7FFF + ((x.u >> 16) & 1);
  return (unsigned short)(r >> 16);
}
__device__ __forceinline__ f32x4 mfma16(short8 a, short8 b, f32x4 c) {
  return __builtin_amdgcn_mfma_f32_16x16x32_bf16(a, b, c, 0, 0, 0);
}

// ---- kernel 0: Wout f32 -> bf16; zero hs pad rows ---------------------------
__global__ __launch_bounds__(256) void k_prep(
    const float* __restrict__ Wout, unsigned short* __restrict__ wb,
    unsigned short* __restrict__ hsb) {
  const int n4 = NV * NH / 4;
  for (int i = blockIdx.x * 256 + threadIdx.x; i < n4; i += gridDim.x * 256) {
    f32x4 v = *(const f32x4*)(Wout + (size_t)i * 4);
    unsigned short o[4];
#pragma unroll
    for (int u = 0; u < 4; ++u) o[u] = f2b(v[u]);
    *(uint64_t*)(wb + (size_t)i * 4) = *(const uint64_t*)o;
  }
  for (int i = blockIdx.x * 256 + threadIdx.x; i < 64 * NH; i += gridDim.x * 256)
    hsb[(size_t)(NT * NB) * NH + i] = 0;   // pad rows 4032..4095
}

// ---- kernel 1: h0 = tanh(enc@Wh^T+bh), c0 = tanh(enc@Wc^T+bc) ---------------
__global__ __launch_bounds__(256) void k_init(
    const float* __restrict__ enc, const float* __restrict__ Wh, const float* __restrict__ bh,
    const float* __restrict__ Wc, const float* __restrict__ bc,
    float* __restrict__ c0, float* __restrict__ h0) {
  int b = blockIdx.x;
  __shared__ float se[NE];
  for (int e = threadIdx.x; e < NE; e += 256) se[e] = enc[b * NE + e];
  __syncthreads();
  for (int j = threadIdx.x; j < NH; j += 256) {
    float dh = 0.f, dc = 0.f;
    const float* wh = Wh + (size_t)j * NE;
    const float* wc = Wc + (size_t)j * NE;
    for (int e = 0; e < NE; e += 4) {
      f32x4 vh = *(const f32x4*)(wh + e);
      f32x4 vc = *(const f32x4*)(wc + e);
#pragma unroll
      for (int u = 0; u < 4; ++u) {
        float x = se[e + u];
        dh += x * vh[u];
        dc += x * vc[u];
      }
    }
    h0[b * NH + j] = tanhf(dh + bh[j]);
    c0[b * NH + j] = tanhf(dc + bc[j]);
  }
}

// ---- kernel 2 (f32): xp[t][b][g] = emb(cap[b][t]) @ W_ih^T + b_ih + b_hh ----
__global__ __launch_bounds__(256) void k_xp(
    const int* __restrict__ cap, const float* __restrict__ emb,
    const float* __restrict__ Wih, const float* __restrict__ bih, const float* __restrict__ bhh,
    float* __restrict__ xp) {
  int t = blockIdx.x;
  int g0 = blockIdx.y * 64;
  int b = threadIdx.x & 63;
  int gg = threadIdx.x >> 6;
  __shared__ float wl[64 * 32];

  int tok = cap[b * 64 + t];          // captions (64,64) row-major
  const float* er = emb + (size_t)tok * NE;

  float acc[16];
#pragma unroll
  for (int i = 0; i < 16; ++i) acc[i] = 0.f;

  for (int k0 = 0; k0 < NE; k0 += 32) {
    __syncthreads();
#pragma unroll
    for (int i = 0; i < 2; ++i) {
      int s = threadIdx.x + 256 * i;
      int gr = s >> 3, c4 = s & 7;
      *(f32x4*)(wl + gr * 32 + c4 * 4) =
          *(const f32x4*)(Wih + (size_t)(g0 + gr) * NE + k0 + c4 * 4);
    }
    __syncthreads();
    f32x4 e4[8];
#pragma unroll
    for (int u = 0; u < 8; ++u) e4[u] = *(const f32x4*)(er + k0 + u * 4);
#pragma unroll
    for (int k4 = 0; k4 < 8; ++k4) {
#pragma unroll
      for (int i = 0; i < 16; ++i) {
        f32x4 w = *(const f32x4*)(wl + (gg * 16 + i) * 32 + k4 * 4);
#pragma unroll
        for (int u = 0; u < 4; ++u) acc[i] += e4[k4][u] * w[u];
      }
    }
  }
  size_t rb = ((size_t)(t * NB) + b) * NG + g0 + gg * 16;
#pragma unroll
  for (int i = 0; i < 16; ++i) {
    int g = g0 + gg * 16 + i;
    xp[rb + i] = acc[i] + bih[g] + bhh[g];
  }
}

// ---- kernel 3a (f32): one LSTM step, xp precomputed; hs written bf16 --------
__global__ __launch_bounds__(256) void k_step(
    const float* __restrict__ xp_t, const float* __restrict__ Whh,
    const float* __restrict__ h_in, float* __restrict__ c,
    float* __restrict__ h_out, unsigned short* __restrict__ hs_t) {
  int j0 = blockIdx.x * 2;
  int tid = threadIdx.x;
  int b = tid & 63;
  int jl = (tid >> 6) & 1;
  int gh = tid >> 7;
  __shared__ float w8[8 * 512];
  __shared__ float hl[64 * 128];
  __shared__ float gbuf[64 * 2 * 4];

#pragma unroll
  for (int i = 0; i < 4; ++i) {
    int s = tid + 256 * i;
    int r = s >> 7, c4 = s & 127;
    int g = r >> 1, jj = r & 1;
    *(f32x4*)(w8 + r * 512 + c4 * 4) =
        *(const f32x4*)(Whh + (size_t)(g * NH + j0 + jj) * NH + c4 * 4);
  }

  float accA = 0.f, accB = 0.f;
  int rA = 4 * gh + jl;
  int rB = rA + 2;
  int Cb = b & 31;

  for (int k0 = 0; k0 < NH; k0 += 128) {
    __syncthreads();
#pragma unroll
    for (int i = 0; i < 8; ++i) {
      int s = tid + 256 * i;
      int row = s >> 5, c4 = s & 31;
      f32x4 v = *(const f32x4*)(h_in + (size_t)row * NH + k0 + c4 * 4);
      *(f32x4*)(hl + row * 128 + ((c4 ^ (row & 31)) * 4)) = v;
    }
    __syncthreads();
#pragma unroll 8
    for (int k4 = 0; k4 < 32; ++k4) {
      f32x4 hv = *(const f32x4*)(hl + b * 128 + ((k4 ^ Cb) * 4));
      f32x4 wa = *(const f32x4*)(w8 + rA * 512 + k0 + k4 * 4);
      f32x4 wb = *(const f32x4*)(w8 + rB * 512 + k0 + k4 * 4);
#pragma unroll
      for (int u = 0; u < 4; ++u) {
        accA += hv[u] * wa[u];
        accB += hv[u] * wb[u];
      }
    }
  }

  int j = j0 + jl;
  accA += xp_t[(size_t)b * NG + (2 * gh) * NH + j];
  accB += xp_t[(size_t)b * NG + (2 * gh + 1) * NH + j];
  gbuf[(b * 2 + jl) * 4 + 2 * gh] = accA;
  gbuf[(b * 2 + jl) * 4 + 2 * gh + 1] = accB;
  __syncthreads();

  if (tid < 128) {
    int bb = tid & 63, jj = tid >> 6;
    int jx = j0 + jj;
    float gi = gbuf[(bb * 2 + jj) * 4 + 0];
    float gf = gbuf[(bb * 2 + jj) * 4 + 1];
    float gG = gbuf[(bb * 2 + jj) * 4 + 2];
    float go = gbuf[(bb * 2 + jj) * 4 + 3];
    float cn = sigm(gf) * c[bb * NH + jx] + sigm(gi) * tanhf(gG);
    c[bb * NH + jx] = cn;
    float h = sigm(go) * tanhf(cn);
    h_out[bb * NH + jx] = h;
    hs_t[bb * NH + jx] = f2b(h);
  }
}

// ---- kernel 3b (f32): fused LSTM step (no xp buffer); hs written bf16 -------
__global__ __launch_bounds__(256) void k_step_f(
    const int* __restrict__ cap, int t, const float* __restrict__ emb,
    const float* __restrict__ Wih, const float* __restrict__ Whh,
    const float* __restrict__ bih, const float* __restrict__ bhh,
    const float* __restrict__ h_in, float* __restrict__ c,
    float* __restrict__ h_out, unsigned short* __restrict__ hs_t) {
  int j0 = blockIdx.x * 2;
  int tid = threadIdx.x;
  int b = tid & 63;
  int jl = (tid >> 6) & 1;
  int gh = tid >> 7;
  __shared__ float w16[8 * 1024];
  __shared__ float xl[64 * 64];
  __shared__ float gbuf[512];
  __shared__ int   tokL[64];

  if (tid < 64) tokL[tid] = cap[tid * 64 + t];

#pragma unroll
  for (int i = 0; i < 8; ++i) {
    int s = tid + 256 * i;
    int r = s >> 8, c4 = s & 255;
    int g = r >> 1, jj = r & 1;
    int col = c4 * 4;
    const float* src = (col < 512)
        ? (Wih + (size_t)(g * NH + j0 + jj) * NE + col)
        : (Whh + (size_t)(g * NH + j0 + jj) * NH + (col - 512));
    *(f32x4*)(w16 + r * 1024 + col) = *(const f32x4*)src;
  }

  float accA = 0.f, accB = 0.f;
  int rA = 4 * gh + jl;
  int rB = rA + 2;
  int Cb = b & 15;

  for (int kc = 0; kc < 16; ++kc) {
    __syncthreads();
#pragma unroll
    for (int i = 0; i < 4; ++i) {
      int s = tid + 256 * i;
      int row = s >> 4, c4 = s & 15;
      const float* src = (kc < 8)
          ? (emb + (size_t)tokL[row] * NE + kc * 64 + c4 * 4)
          : (h_in + (size_t)row * NH + (kc - 8) * 64 + c4 * 4);
      *(f32x4*)(xl + row * 64 + ((c4 ^ (row & 15)) * 4)) = *(const f32x4*)src;
    }
    __syncthreads();
#pragma unroll
    for (int k4 = 0; k4 < 16; ++k4) {
      f32x4 hv = *(const f32x4*)(xl + b * 64 + ((k4 ^ Cb) * 4));
      f32x4 wa = *(const f32x4*)(w16 + rA * 1024 + kc * 64 + k4 * 4);
      f32x4 wb = *(const f32x4*)(w16 + rB * 1024 + kc * 64 + k4 * 4);
#pragma unroll
      for (int u = 0; u < 4; ++u) {
        accA += hv[u] * wa[u];
        accB += hv[u] * wb[u];
      }
    }
  }

  int j = j0 + jl;
  accA += bih[(2 * gh) * NH + j] + bhh[(2 * gh) * NH + j];
  accB += bih[(2 * gh + 1) * NH + j] + bhh[(2 * gh + 1) * NH + j];
  gbuf[(b * 2 + jl) * 4 + 2 * gh] = accA;
  gbuf[(b * 2 + jl) * 4 + 2 * gh + 1] = accB;
  __syncthreads();

  if (tid < 128) {
    int bb = tid & 63, jj = tid >> 6;
    int jx = j0 + jj;
    float gi = gbuf[(bb * 2 + jj) * 4 + 0];
    float gf = gbuf[(bb * 2 + jj) * 4 + 1];
    float gG = gbuf[(bb * 2 + jj) * 4 + 2];
    float go = gbuf[(bb * 2 + jj) * 4 + 3];
    float cn = sigm(gf) * c[bb * NH + jx] + sigm(gi) * tanhf(gG);
    c[bb * NH + jx] = cn;
    float h = sigm(go) * tanhf(cn);
    h_out[bb * NH + jx] = h;
    hs_t[bb * NH + jx] = f2b(h);
  }
}

// ---- kernel 4: logits = hs_bf16 @ WoutBf^T + bout, f32 out, (b,t,v) ---------
// M=4032 (pad 4096) x N=32000, K=512. 128x128 tile, BK=64, 4 waves 2x2. T2 swz.
__global__ __launch_bounds__(256) void k_logits_m(
    const unsigned short* __restrict__ hsb, const unsigned short* __restrict__ wb,
    const float* __restrict__ bout, float* __restrict__ out) {
  __shared__ unsigned short As[128 * 64];
  __shared__ unsigned short Bs[128 * 64];
  int m0 = blockIdx.x * 128;
  int n0 = blockIdx.y * 128;
  int tid = threadIdx.x;
  int lane = tid & 63;
  int l15 = lane & 15;
  int kl = (lane >> 4) * 8;
  int w = tid >> 6;
  int wr = w >> 1, wc = w & 1;

  f32x4 acc[4][4];
#pragma unroll
  for (int i = 0; i < 4; ++i)
#pragma unroll
    for (int j = 0; j < 4; ++j) acc[i][j] = (f32x4){0.f, 0.f, 0.f, 0.f};

  for (int k0 = 0; k0 < NH; k0 += 64) {
    short8 ta[4], tb[4];
#pragma unroll
    for (int cc = 0; cc < 4; ++cc) {
      int idx = cc * 2048 + tid * 8;       // element index in 128x64 tile
      int row = idx >> 6;
      int ke = idx & 63;
      ta[cc] = *(const short8*)(hsb + (size_t)(m0 + row) * NH + k0 + ke);
      tb[cc] = *(const short8*)(wb + (size_t)(n0 + row) * NH + k0 + ke);
    }
    __syncthreads();                       // prior iter's LDS reads done
#pragma unroll
    for (int cc = 0; cc < 4; ++cc) {
      int idx = cc * 2048 + tid * 8;
      int row = idx >> 6;
      int ke = (idx & 63) ^ ((row & 7) << 3);   // T2 XOR swizzle
      *(short8*)(As + row * 64 + ke) = ta[cc];
      *(short8*)(Bs + row * 64 + ke) = tb[cc];
    }
    __syncthreads();
#pragma unroll
    for (int kk = 0; kk < 64; kk += 32) {
      short8 a[4], b[4];
#pragma unroll
      for (int mi = 0; mi < 4; ++mi) {
        int row = wr * 64 + mi * 16 + l15;
        a[mi] = *(const short8*)(As + row * 64 + ((kk + kl) ^ ((row & 7) << 3)));
      }
#pragma unroll
      for (int ni = 0; ni < 4; ++ni) {
        int row = wc * 64 + ni * 16 + l15;
        b[ni] = *(const short8*)(Bs + row * 64 + ((kk + kl) ^ ((row & 7) << 3)));
      }
#pragma unroll
      for (int mi = 0; mi < 4; ++mi)
#pragma unroll
        for (int ni = 0; ni < 4; ++ni)
          acc[mi][ni] = mfma16(a[mi], b[ni], acc[mi][ni]);
    }
  }
#pragma unroll
  for (int mi = 0; mi < 4; ++mi) {
#pragma unroll
    for (int ni = 0; ni < 4; ++ni) {
      int v = n0 + wc * 64 + ni * 16 + l15;
      float bo = bout[v];
#pragma unroll
      for (int r = 0; r < 4; ++r) {
        int m = m0 + wr * 64 + mi * 16 + (lane >> 4) * 4 + r;
        if (m < NT * NB) {
          int t = m >> 6, b = m & 63;
          out[(size_t)b * (NT * NV) + (size_t)t * NV + v] = acc[mi][ni][r] + bo;
        }
      }
    }
  }
}

extern "C" void kernel_launch(void* const* d_in, const int* in_sizes, int n_in,
                              void* d_out, int out_size, void* d_ws, size_t ws_size,
                              hipStream_t stream) {
  const float* enc  = (const float*)d_in[0];
  const int*   cap  = (const int*)d_in[1];
  const float* emb  = (const float*)d_in[2];
  const float* Wih  = (const float*)d_in[3];
  const float* Whh  = (const float*)d_in[4];
  const float* bih  = (const float*)d_in[5];
  const float* bhh  = (const float*)d_in[6];
  const float* Wh   = (const float*)d_in[7];
  const float* bh   = (const float*)d_in[8];
  const float* Wc   = (const float*)d_in[9];
  const float* bc   = (const float*)d_in[10];
  const float* Wout = (const float*)d_in[11];
  const float* bout = (const float*)d_in[12];
  float* out = (float*)d_out;   // FLOAT32 output

  char* ws = (char*)d_ws;
  constexpr size_t C_OFF   = 0;
  constexpr size_t HA_OFF  = C_OFF + (size_t)NB * NH * 4;          // 131072
  constexpr size_t HB_OFF  = HA_OFF + (size_t)NB * NH * 4;         // 262144
  constexpr size_t HSB_OFF = HB_OFF + (size_t)NB * NH * 4;         // 393216
  constexpr size_t WB_OFF  = HSB_OFF + (size_t)4096 * NH * 2;      // 4,587,520
  constexpr size_t XP_OFF  = WB_OFF + (size_t)NV * NH * 2;         // 37,355,520
  constexpr size_t NEED_XP = XP_OFF + (size_t)NT * NB * NG * 4;    // 70,385,664
  float* c  = (float*)(ws + C_OFF);
  float* hA = (float*)(ws + HA_OFF);
  float* hB = (float*)(ws + HB_OFF);
  unsigned short* hsb = (unsigned short*)(ws + HSB_OFF);
  unsigned short* wb  = (unsigned short*)(ws + WB_OFF);
  float* xp = (float*)(ws + XP_OFF);

  k_prep<<<1024, 256, 0, stream>>>(Wout, wb, hsb);
  k_init<<<NB, 256, 0, stream>>>(enc, Wh, bh, Wc, bc, c, hA);

  if (ws_size >= NEED_XP) {
    dim3 g2(NT, NG / 64);
    k_xp<<<g2, 256, 0, stream>>>(cap, emb, Wih, bih, bhh, xp);
    for (int t = 0; t < NT; ++t) {
      const float* h_in = (t & 1) ? hB : hA;
      float* h_out      = (t & 1) ? hA : hB;
      k_step<<<256, 256, 0, stream>>>(xp + (size_t)t * NB * NG, Whh, h_in, c,
                                      h_out, hsb + (size_t)t * NB * NH);
    }
  } else {
    for (int t = 0; t < NT; ++t) {
      const float* h_in = (t & 1) ? hB : hA;
      float* h_out      = (t & 1) ? hA : hB;
      k_step_f<<<256, 256, 0, stream>>>(cap, t, emb, Wih, Whh, bih, bhh, h_in, c,
                                        h_out, hsb + (size_t)t * NB * NH);
    }
  }

  dim3 g4(32, NV / 128);   // M-tiles x N-tiles; consecutive x share Wout panel
  k_logits_m<<<g4, 256, 0, stream>>>(hsb, wb, bout, out);
}